// Round 14
// baseline (1665.266 us; speedup 1.0000x reference)
//
#include <hip/hip_runtime.h>

#define N_NODES 100000
#define M_PAD 100096   // 782 * 128
#define N_EDGES 3200000
#define DIM 512
#define SLOTS 80
#define NEG_SLOPE 0.01f
#define HROW 50048     // 391*128, pipeline half split
#define HTIL 391       // h0 tiles
#define NTIL 782       // M_PAD / 128
#define NB_H0 12512    // HROW/4 spmm blocks
#define NB_H1 12488    // (N_NODES-HROW)/4

// k_setup block partition
#define B_PRE 12500            // N_EDGES / 256
#define B_WT (B_PRE + 2048)    // 2*DIM*DIM / 256
#define B_WP (B_WT + 129)      // 516 wave-tasks / 4
#define B_FEAT (B_WP + 25000)  // N_NODES / 4

typedef _Float16 f16;
typedef _Float16 f16x8 __attribute__((ext_vector_type(8)));
typedef float f32x4 __attribute__((ext_vector_type(4)));

__device__ __forceinline__ void load_lds16(const void* g, void* l) {
  __builtin_amdgcn_global_load_lds(
      (const __attribute__((address_space(1))) void*)g,
      (__attribute__((address_space(3))) void*)l, 16, 0, 0);
}

// ---------------- fused setup ----------------
__global__ void k_setup(const int* __restrict__ src, const int* __restrict__ dst,
                        int* __restrict__ cnt_o, int* __restrict__ cnt_i,
                        int* __restrict__ ell,
                        const float* __restrict__ W0, const float* __restrict__ W1,
                        f16* __restrict__ Wt,
                        const float* __restrict__ W2, const float* __restrict__ b2,
                        const float* __restrict__ pW, const float* __restrict__ pb,
                        float* __restrict__ wt_vec, float* __restrict__ c_out,
                        const float* __restrict__ weight, const int* __restrict__ sig,
                        const float* __restrict__ emb, const float* __restrict__ linW,
                        const float* __restrict__ linb, f16* __restrict__ Xs) {
  const int bid = blockIdx.x;
  const int tid = threadIdx.x;
  if (bid < B_PRE) {
    int e = bid * 256 + tid;
    int s = src[e];
    atomicAdd(&cnt_o[s], 1);
    int d = dst[e];
    int p = atomicAdd(&cnt_i[d], 1);
    if (p < SLOTS) ell[(size_t)d * SLOTS + p] = s;
  } else if (bid < B_WT) {
    int idx = (bid - B_PRE) * 256 + tid;
    int l = idx >> 18;
    int r = idx & 262143;
    int n = r >> 9, k = r & 511;
    const float* W = l ? W1 : W0;
    Wt[idx] = (f16)W[k * DIM + n];
  } else if (bid < B_WP) {
    int wid = tid >> 6, lane = tid & 63;
    int t = (bid - B_WT) * 4 + wid;
    if (t < DIM) {
      float s = 0.f;
#pragma unroll
      for (int n = 0; n < DIM; n += 64) s += W2[t * DIM + n + lane] * pW[n + lane];
#pragma unroll
      for (int off = 32; off; off >>= 1) s += __shfl_down(s, off, 64);
      if (lane == 0) wt_vec[t] = s;
    } else if (t == DIM) {
      float s = 0.f;
#pragma unroll
      for (int n = 0; n < DIM; n += 64) s += b2[n + lane] * pW[n + lane];
#pragma unroll
      for (int off = 32; off; off >>= 1) s += __shfl_down(s, off, 64);
      if (lane == 0) c_out[0] = s + pb[0];
    }
  } else {
    int wid = tid >> 6, lane = tid & 63;
    int node = (bid - B_WP) * 4 + wid;
    float w = weight[node];
    int sg = sig[node];
    float s0 = emb[sg * 2], s1 = emb[sg * 2 + 1];
    int d0 = lane * 8;
    f16x8 v;
#pragma unroll
    for (int k = 0; k < 8; k++) {
      int d = d0 + k;
      v[k] = (f16)(w * linW[d] + s0 * linW[DIM + d] + s1 * linW[2 * DIM + d] + linb[d]);
    }
    *(f16x8*)(Xs + (size_t)node * DIM + d0) = v;
  }
}

__global__ void k_norms(const int* __restrict__ cnt_o, const int* __restrict__ cnt_i,
                        float* __restrict__ n_out, float* __restrict__ n_in) {
  int i = blockIdx.x * blockDim.x + threadIdx.x;
  if (i < N_NODES) {
    n_out[i] = rsqrtf((float)cnt_o[i] + 1.0f);
    n_in[i] = rsqrtf((float)cnt_i[i] + 1.0f);
  }
}

// ---------------- bodies ----------------

__device__ __forceinline__ void spmm_body(const f16* __restrict__ Xlo,
                                          const f16* __restrict__ Xhi, int H,
                                          f16* __restrict__ A,
                                          const int* __restrict__ ell,
                                          const int* __restrict__ cnt_i,
                                          const float* __restrict__ n_in,
                                          const float* __restrict__ n_out,  // null => plain
                                          int node, int lane) {
  int d0 = lane * 8;
  float acc[8];
  {
    const f16* sb = (node < H ? Xlo : Xhi) + (size_t)node * DIM + d0;
    f16x8 v = *(const f16x8*)sb;
    float ss = n_out ? n_out[node] : 1.f;
#pragma unroll
    for (int k = 0; k < 8; k++) acc[k] = ss * (float)v[k];
  }
  int deg = cnt_i[node];
  if (deg > SLOTS) deg = SLOTS;
  const int* erow = ell + (size_t)node * SLOTS;
  int j = 0;
  if (n_out) {
    for (; j + 8 <= deg; j += 8) {
      int ix[8];
#pragma unroll
      for (int u = 0; u < 8; u++) ix[u] = erow[j + u];
      float sc[8];
#pragma unroll
      for (int u = 0; u < 8; u++) sc[u] = n_out[ix[u]];
      f16x8 v[8];
#pragma unroll
      for (int u = 0; u < 8; u++)
        v[u] = *(const f16x8*)((ix[u] < H ? Xlo : Xhi) + (size_t)ix[u] * DIM + d0);
#pragma unroll
      for (int u = 0; u < 8; u++)
#pragma unroll
        for (int k = 0; k < 8; k++) acc[k] += sc[u] * (float)v[u][k];
    }
    for (; j < deg; ++j) {
      int sn = erow[j];
      float sc = n_out[sn];
      f16x8 v = *(const f16x8*)((sn < H ? Xlo : Xhi) + (size_t)sn * DIM + d0);
#pragma unroll
      for (int k = 0; k < 8; k++) acc[k] += sc * (float)v[k];
    }
  } else {
    for (; j + 8 <= deg; j += 8) {
      int ix[8];
#pragma unroll
      for (int u = 0; u < 8; u++) ix[u] = erow[j + u];
      f16x8 v[8];
#pragma unroll
      for (int u = 0; u < 8; u++)
        v[u] = *(const f16x8*)((ix[u] < H ? Xlo : Xhi) + (size_t)ix[u] * DIM + d0);
#pragma unroll
      for (int u = 0; u < 8; u++)
#pragma unroll
        for (int k = 0; k < 8; k++) acc[k] += (float)v[u][k];
    }
    for (; j < deg; ++j) {
      int sn = erow[j];
      f16x8 v = *(const f16x8*)((sn < H ? Xlo : Xhi) + (size_t)sn * DIM + d0);
#pragma unroll
      for (int k = 0; k < 8; k++) acc[k] += (float)v[k];
    }
  }
  float ni = n_in[node];
  f16x8 o;
#pragma unroll
  for (int k = 0; k < 8; k++) o[k] = (f16)(acc[k] * ni);
  __builtin_nontemporal_store(o, (f16x8*)(A + (size_t)node * DIM + d0));
}

__device__ __forceinline__ void gemm_body(char* smem, float* yred,
                                          const f16* __restrict__ A,
                                          const f16* __restrict__ Wt,
                                          const float* __restrict__ bias,
                                          const float* __restrict__ n_out,
                                          f16* __restrict__ Y,
                                          const float* __restrict__ wt_vec,
                                          float* __restrict__ yv,
                                          int bx, int by, int tid) {
  const int wid = tid >> 6, lane = tid & 63;
  const int lr = lane & 15, lk = lane >> 4;
  const int wr = wid >> 1, wc = wid & 1;
  const int cb = bx * 128;
  const int rb = by * 128;
  const int ls = lane >> 3;
  const int ss = lane & 7;

  f32x4 acc[4][4];
#pragma unroll
  for (int i = 0; i < 4; i++)
#pragma unroll
    for (int j = 0; j < 4; j++) acc[i][j] = (f32x4){0.f, 0.f, 0.f, 0.f};

  for (int kb = 0; kb < DIM; kb += 64) {
#pragma unroll
    for (int i = 0; i < 4; i++) {
      int c = wid * 4 + i;
      int r = c * 8 + ls;
      int goff = (ss * 16) ^ ((r & 7) << 4);
      const char* ga = (const char*)A + ((size_t)(rb + r) * DIM + kb) * 2 + goff;
      load_lds16(ga, smem + c * 1024);
      const char* gw = (const char*)Wt + ((size_t)(cb + r) * DIM + kb) * 2 + goff;
      load_lds16(gw, smem + 16384 + c * 1024);
    }
    __syncthreads();
#pragma unroll
    for (int kk = 0; kk < 2; kk++) {
      f16x8 a[4], b[4];
#pragma unroll
      for (int fm = 0; fm < 4; fm++) {
        int row = wr * 64 + fm * 16 + lr;
        int byt = row * 128 + ((kk * 64 + lk * 16) ^ ((row & 7) << 4));
        a[fm] = *(const f16x8*)(smem + byt);
      }
#pragma unroll
      for (int fn = 0; fn < 4; fn++) {
        int row = wc * 64 + fn * 16 + lr;
        int byt = row * 128 + ((kk * 64 + lk * 16) ^ ((row & 7) << 4));
        b[fn] = *(const f16x8*)(smem + 16384 + byt);
      }
#pragma unroll
      for (int fm = 0; fm < 4; fm++)
#pragma unroll
        for (int fn = 0; fn < 4; fn++)
          acc[fm][fn] = __builtin_amdgcn_mfma_f32_16x16x32_f16(a[fm], b[fn], acc[fm][fn], 0, 0, 0);
    }
    __syncthreads();
  }

  if (yv == nullptr) {
#pragma unroll
    for (int fn = 0; fn < 4; fn++) {
      int col = cb + wc * 64 + fn * 16 + lr;
      float bv = bias[col];
#pragma unroll
      for (int fm = 0; fm < 4; fm++) {
#pragma unroll
        for (int r = 0; r < 4; r++) {
          int row = rb + wr * 64 + fm * 16 + lk * 4 + r;
          if (row < N_NODES) {
            float v = acc[fm][fn][r] + bv;
            v = (v >= 0.f) ? v : NEG_SLOPE * v;
            v *= n_out[row];
            Y[(size_t)row * DIM + col] = (f16)v;
          }
        }
      }
    }
  } else {
    if (tid < 128) yred[tid] = 0.f;
    __syncthreads();
#pragma unroll
    for (int fm = 0; fm < 4; fm++) {
#pragma unroll
      for (int r = 0; r < 4; r++) {
        int rloc = wr * 64 + fm * 16 + lk * 4 + r;
        int row = rb + rloc;
        float p = 0.f;
#pragma unroll
        for (int fn = 0; fn < 4; fn++) {
          int col = cb + wc * 64 + fn * 16 + lr;
          float v = acc[fm][fn][r] + bias[col];
          v = (v >= 0.f) ? v : NEG_SLOPE * v;
          p += v * wt_vec[col];
        }
        if (row < N_NODES) atomicAdd(&yred[rloc & 127], p * n_out[row]);
      }
    }
    __syncthreads();
    if (tid < 128) {
      int row = rb + tid;
      if (row < N_NODES) atomicAdd(&yv[row], yred[tid]);
    }
  }
}

// ---------------- kernels ----------------

__global__ void k_spmm(const f16* __restrict__ Xlo, const f16* __restrict__ Xhi, int H,
                       f16* __restrict__ A, const int* __restrict__ ell,
                       const int* __restrict__ cnt_i, const float* __restrict__ n_in,
                       const float* __restrict__ n_out, int node0) {
  int wid = threadIdx.x >> 6, lane = threadIdx.x & 63;
  int node = node0 + blockIdx.x * 4 + wid;
  if (node >= N_NODES) return;
  spmm_body(Xlo, Xhi, H, A, ell, cnt_i, n_in, n_out, node, lane);
}

__global__ __launch_bounds__(256) void k_gemm(const f16* __restrict__ A, const f16* __restrict__ Wt,
                                              const float* __restrict__ bias,
                                              const float* __restrict__ n_out,
                                              f16* __restrict__ Y,
                                              const float* __restrict__ wt_vec,
                                              float* __restrict__ yv, int tile_off) {
  __shared__ __align__(1024) char smem[32768];
  __shared__ float yred[128];
  gemm_body(smem, yred, A, Wt, bias, n_out, Y, wt_vec, yv,
            blockIdx.x, blockIdx.y + tile_off, threadIdx.x);
}

// mixed dispatch: blocks [0, G4) = gemm tiles (by = bid>>2, bx = bid&3),
// rest = spmm nodes starting at node0.
__global__ __launch_bounds__(256) void k_mix(const f16* __restrict__ Xlo,
                                             const f16* __restrict__ Xhi, int H,
                                             f16* __restrict__ A,
                                             const int* __restrict__ ell,
                                             const int* __restrict__ cnt_i,
                                             const float* __restrict__ n_in,
                                             const float* __restrict__ n_out_spmm,
                                             const f16* __restrict__ Ag,
                                             const f16* __restrict__ Wt,
                                             const float* __restrict__ bias,
                                             const float* __restrict__ n_out,
                                             f16* __restrict__ Y,
                                             const float* __restrict__ wt_vec,
                                             float* __restrict__ yv,
                                             int G4, int node0) {
  __shared__ __align__(1024) char smem[32768];
  __shared__ float yred[128];
  const int bid = blockIdx.x;
  if (bid < G4) {
    gemm_body(smem, yred, Ag, Wt, bias, n_out, Y, wt_vec, yv,
              bid & 3, bid >> 2, threadIdx.x);
  } else {
    int wid = threadIdx.x >> 6, lane = threadIdx.x & 63;
    int node = node0 + (bid - G4) * 4 + wid;
    if (node >= N_NODES) return;
    spmm_body(Xlo, Xhi, H, A, ell, cnt_i, n_in, n_out_spmm, node, lane);
  }
}

__global__ void k_sagg(const float* __restrict__ y, const int* __restrict__ ell,
                       const int* __restrict__ cnt_i, const float* __restrict__ n_in,
                       const float* __restrict__ c_out, float* __restrict__ out) {
  int i = blockIdx.x * blockDim.x + threadIdx.x;
  if (i >= N_NODES) return;
  int deg = cnt_i[i];
  if (deg > SLOTS) deg = SLOTS;
  const int* erow = ell + (size_t)i * SLOTS;
  float s = y[i];
  int j = 0;
  for (; j + 8 <= deg; j += 8) {
    int4 a = *(const int4*)(erow + j);
    int4 b = *(const int4*)(erow + j + 4);
    s += y[a.x] + y[a.y] + y[a.z] + y[a.w];
    s += y[b.x] + y[b.y] + y[b.z] + y[b.w];
  }
  for (; j < deg; ++j) s += y[erow[j]];
  out[i] = n_in[i] * s + c_out[0];
}

extern "C" void kernel_launch(void* const* d_in, const int* in_sizes, int n_in_cnt,
                              void* d_out, int out_size, void* d_ws, size_t ws_size,
                              hipStream_t stream) {
  const float* weight = (const float*)d_in[0];
  const int* sig = (const int*)d_in[1];
  const int* src = (const int*)d_in[2];
  const int* dst = (const int*)d_in[3];
  const float* emb = (const float*)d_in[4];
  const float* linW = (const float*)d_in[5];
  const float* linb = (const float*)d_in[6];
  const float* W0 = (const float*)d_in[7];
  const float* b0 = (const float*)d_in[8];
  const float* W1 = (const float*)d_in[9];
  const float* b1 = (const float*)d_in[10];
  const float* W2 = (const float*)d_in[11];
  const float* b2 = (const float*)d_in[12];
  const float* pW = (const float*)d_in[13];
  const float* pb = (const float*)d_in[14];
  float* out = (float*)d_out;

  char* ws = (char*)d_ws;
  size_t off = 0;
  auto alloc = [&](size_t bytes) {
    void* p = ws + off;
    off += (bytes + 255) & ~(size_t)255;
    return p;
  };
  int* cnt_o = (int*)alloc((size_t)N_NODES * 4);   // cnt_o+cnt_i+yv: one memset
  int* cnt_i = (int*)alloc((size_t)N_NODES * 4);
  float* yv = (float*)alloc((size_t)N_NODES * 4);
  float* n_out = (float*)alloc((size_t)N_NODES * 4);
  float* n_in = (float*)alloc((size_t)N_NODES * 4);
  int* ell = (int*)alloc((size_t)N_NODES * SLOTS * 4);
  f16* Wt = (f16*)alloc((size_t)2 * DIM * DIM * 2);
  float* wt_vec = (float*)alloc((size_t)DIM * 4);
  float* c_out = (float*)alloc(256);
  f16* B0 = (f16*)alloc((size_t)M_PAD * DIM * 2);
  f16* B1 = (f16*)alloc((size_t)M_PAD * DIM * 2);

  // layer-0 gemm spill buffer: as many 128-row tiles as the workspace allows
  size_t avail = (ws_size > off) ? (ws_size - off) : 0;
  int q = (int)(avail / ((size_t)128 * DIM * 2));
  if (q > HTIL) q = HTIL;
  f16* SP = (f16*)(ws + off);
  const int H = q * 128;

  dim3 blk(256);
  hipMemsetAsync(cnt_o, 0, (char*)n_out - (char*)cnt_o, stream);
  k_setup<<<B_FEAT, blk, 0, stream>>>(src, dst, cnt_o, cnt_i, ell,
                                      W0, W1, Wt, W2, b2, pW, pb, wt_vec, c_out,
                                      weight, sig, emb, linW, linb, B0);
  k_norms<<<(N_NODES + 255) / 256, blk, 0, stream>>>(cnt_o, cnt_i, n_out, n_in);

  // ---- layer 0: X=B0 (unscaled; spmm applies n_out), A=B1, Y -> SP[0,H)+B0[H,M) ----
  if (q > 0) {
    k_spmm<<<NB_H0, blk, 0, stream>>>(B0, B0, 0, B1, ell, cnt_i, n_in, n_out, 0);
    k_mix<<<q * 4 + NB_H1, blk, 0, stream>>>(B0, B0, 0, B1, ell, cnt_i, n_in, n_out,
                                             B1, Wt, b0, n_out, SP, nullptr, nullptr,
                                             q * 4, HROW);
    dim3 gg(4, NTIL - q);
    k_gemm<<<gg, blk, 0, stream>>>(B1, Wt, b0, n_out, B0, nullptr, nullptr, q);
  } else {
    k_spmm<<<N_NODES / 4, blk, 0, stream>>>(B0, B0, 0, B1, ell, cnt_i, n_in, n_out, 0);
    dim3 gg(4, NTIL);
    k_gemm<<<gg, blk, 0, stream>>>(B1, Wt, b0, n_out, B0, nullptr, nullptr, 0);
  }

  // ---- layer 1: X = SP[0,H)+B0[H,M) (pre-scaled), A=B1, fused GEMV -> yv ----
  k_spmm<<<NB_H0, blk, 0, stream>>>(SP, B0, H, B1, ell, cnt_i, n_in, nullptr, 0);
  k_mix<<<HTIL * 4 + NB_H1, blk, 0, stream>>>(SP, B0, H, B1, ell, cnt_i, n_in, nullptr,
                                              B1, Wt + (size_t)DIM * DIM, b1, n_out,
                                              nullptr, wt_vec, yv, HTIL * 4, HROW);
  dim3 gg2(4, NTIL - HTIL);
  k_gemm<<<gg2, blk, 0, stream>>>(B1, Wt + (size_t)DIM * DIM, b1, n_out, nullptr,
                                  wt_vec, yv, HTIL);

  k_sagg<<<(N_NODES + 255) / 256, blk, 0, stream>>>(yv, ell, cnt_i, n_in, c_out, out);
}

// Round 15
// 1635.267 us; speedup vs baseline: 1.0183x; 1.0183x over previous
//
#include <hip/hip_runtime.h>

#define N_NODES 100000
#define M_PAD 100096   // 782 * 128
#define N_EDGES 3200000
#define DIM 512
#define SLOTS 80
#define NEG_SLOPE 0.01f

// k_setup block partition
#define B_PRE 12500            // N_EDGES / 256
#define B_WT (B_PRE + 2048)    // 2*DIM*DIM / 256
#define B_WP (B_WT + 129)      // 516 wave-tasks / 4
#define B_FEAT (B_WP + 25000)  // N_NODES / 4

typedef _Float16 f16;
typedef _Float16 f16x8 __attribute__((ext_vector_type(8)));
typedef float f32x4 __attribute__((ext_vector_type(4)));

__device__ __forceinline__ void load_lds16(const void* g, void* l) {
  __builtin_amdgcn_global_load_lds(
      (const __attribute__((address_space(1))) void*)g,
      (__attribute__((address_space(3))) void*)l, 16, 0, 0);
}

// ---------------- fused setup ----------------
// cnt_op: P partial out-degree histograms (P-way split cuts per-line RMW
// contention P x); cnt_i: single-copy ELL append cursor (needs unique slots).
__global__ void k_setup(const int* __restrict__ src, const int* __restrict__ dst,
                        int* __restrict__ cnt_op, int pmask,
                        int* __restrict__ cnt_i, int* __restrict__ ell,
                        const float* __restrict__ W0, const float* __restrict__ W1,
                        f16* __restrict__ Wt,
                        const float* __restrict__ W2, const float* __restrict__ b2,
                        const float* __restrict__ pW, const float* __restrict__ pb,
                        float* __restrict__ wt_vec, float* __restrict__ c_out,
                        const float* __restrict__ weight, const int* __restrict__ sig,
                        const float* __restrict__ emb, const float* __restrict__ linW,
                        const float* __restrict__ linb, f16* __restrict__ Xs) {
  const int bid = blockIdx.x;
  const int tid = threadIdx.x;
  if (bid < B_PRE) {
    int e = bid * 256 + tid;
    int s = src[e];
    atomicAdd(&cnt_op[(size_t)(bid & pmask) * N_NODES + s], 1);
    int d = dst[e];
    int p = atomicAdd(&cnt_i[d], 1);
    if (p < SLOTS) ell[(size_t)d * SLOTS + p] = s;
  } else if (bid < B_WT) {
    int idx = (bid - B_PRE) * 256 + tid;
    int l = idx >> 18;
    int r = idx & 262143;
    int n = r >> 9, k = r & 511;
    const float* W = l ? W1 : W0;
    Wt[idx] = (f16)W[k * DIM + n];
  } else if (bid < B_WP) {
    int wid = tid >> 6, lane = tid & 63;
    int t = (bid - B_WT) * 4 + wid;
    if (t < DIM) {
      float s = 0.f;
#pragma unroll
      for (int n = 0; n < DIM; n += 64) s += W2[t * DIM + n + lane] * pW[n + lane];
#pragma unroll
      for (int off = 32; off; off >>= 1) s += __shfl_down(s, off, 64);
      if (lane == 0) wt_vec[t] = s;
    } else if (t == DIM) {
      float s = 0.f;
#pragma unroll
      for (int n = 0; n < DIM; n += 64) s += b2[n + lane] * pW[n + lane];
#pragma unroll
      for (int off = 32; off; off >>= 1) s += __shfl_down(s, off, 64);
      if (lane == 0) c_out[0] = s + pb[0];
    }
  } else {
    int wid = tid >> 6, lane = tid & 63;
    int node = (bid - B_WP) * 4 + wid;
    float w = weight[node];
    int sg = sig[node];
    float s0 = emb[sg * 2], s1 = emb[sg * 2 + 1];
    int d0 = lane * 8;
    f16x8 v;
#pragma unroll
    for (int k = 0; k < 8; k++) {
      int d = d0 + k;
      v[k] = (f16)(w * linW[d] + s0 * linW[DIM + d] + s1 * linW[2 * DIM + d] + linb[d]);
    }
    *(f16x8*)(Xs + (size_t)node * DIM + d0) = v;
  }
}

// n_out from P partial histograms; n_in from append cursor (== in-degree)
__global__ void k_norms(const int* __restrict__ cnt_op, int nparts,
                        const int* __restrict__ cnt_i,
                        float* __restrict__ n_out, float* __restrict__ n_in) {
  int i = blockIdx.x * blockDim.x + threadIdx.x;
  if (i < N_NODES) {
    int d = 0;
    for (int p = 0; p < nparts; p++) d += cnt_op[(size_t)p * N_NODES + i];
    n_out[i] = rsqrtf((float)d + 1.0f);
    n_in[i] = rsqrtf((float)cnt_i[i] + 1.0f);
  }
}

// ---------------- model ----------------

// A[i] = n_in[i] * (scale(i)*X[i] + sum_e scale(src)*X[src_e]);
// scale = n_out if n_out != null else 1. Wave per node, ELL gather unrolled 8x.
__global__ void k_spmm(const f16* __restrict__ Xs, f16* __restrict__ A,
                       const int* __restrict__ ell, const int* __restrict__ cnt_i,
                       const float* __restrict__ n_in, const float* __restrict__ n_out) {
  int wid = threadIdx.x >> 6, lane = threadIdx.x & 63;
  int node = blockIdx.x * 4 + wid;
  int d0 = lane * 8;
  float acc[8];
  {
    f16x8 v = *(const f16x8*)(Xs + (size_t)node * DIM + d0);
    float ss = n_out ? n_out[node] : 1.f;
#pragma unroll
    for (int k = 0; k < 8; k++) acc[k] = ss * (float)v[k];
  }
  int deg = cnt_i[node];
  if (deg > SLOTS) deg = SLOTS;
  const int* erow = ell + (size_t)node * SLOTS;
  const f16* base = Xs + d0;
  int j = 0;
  if (n_out) {
    for (; j + 8 <= deg; j += 8) {
      int ix[8];
#pragma unroll
      for (int u = 0; u < 8; u++) ix[u] = erow[j + u];
      float sc[8];
#pragma unroll
      for (int u = 0; u < 8; u++) sc[u] = n_out[ix[u]];
      f16x8 v[8];
#pragma unroll
      for (int u = 0; u < 8; u++) v[u] = *(const f16x8*)(base + (size_t)ix[u] * DIM);
#pragma unroll
      for (int u = 0; u < 8; u++)
#pragma unroll
        for (int k = 0; k < 8; k++) acc[k] += sc[u] * (float)v[u][k];
    }
    for (; j < deg; ++j) {
      int sn = erow[j];
      float sc = n_out[sn];
      f16x8 v = *(const f16x8*)(base + (size_t)sn * DIM);
#pragma unroll
      for (int k = 0; k < 8; k++) acc[k] += sc * (float)v[k];
    }
  } else {
    for (; j + 8 <= deg; j += 8) {
      int ix[8];
#pragma unroll
      for (int u = 0; u < 8; u++) ix[u] = erow[j + u];
      f16x8 v[8];
#pragma unroll
      for (int u = 0; u < 8; u++) v[u] = *(const f16x8*)(base + (size_t)ix[u] * DIM);
#pragma unroll
      for (int u = 0; u < 8; u++)
#pragma unroll
        for (int k = 0; k < 8; k++) acc[k] += (float)v[u][k];
    }
    for (; j < deg; ++j) {
      int sn = erow[j];
      f16x8 v = *(const f16x8*)(base + (size_t)sn * DIM);
#pragma unroll
      for (int k = 0; k < 8; k++) acc[k] += (float)v[k];
    }
  }
  float ni = n_in[node];
  f16x8 o;
#pragma unroll
  for (int k = 0; k < 8; k++) o[k] = (f16)(acc[k] * ni);
  __builtin_nontemporal_store(o, (f16x8*)(A + (size_t)node * DIM + d0));
}

// yv==null: Y = n_out*leaky(A@W+b). else: yv[row] += n_out[row]*(leaky(A@W+b).wt_vec).
// LDS-staged 128x128 tile, BK=64, global_load_lds w16 w/ pre-swizzled source,
// XOR-swizzled ds_read. 256 thr = 4 waves (2x2), wave tile 64x64.
__global__ __launch_bounds__(256) void k_gemm(const f16* __restrict__ A, const f16* __restrict__ Wt,
                                              const float* __restrict__ bias,
                                              const float* __restrict__ n_out,
                                              f16* __restrict__ Y,
                                              const float* __restrict__ wt_vec,
                                              float* __restrict__ yv) {
  __shared__ __align__(1024) char smem[32768];
  __shared__ float yred[128];
  const int tid = threadIdx.x;
  const int wid = tid >> 6, lane = tid & 63;
  const int lr = lane & 15, lk = lane >> 4;
  const int wr = wid >> 1, wc = wid & 1;
  const int cb = blockIdx.x * 128;
  const int rb = blockIdx.y * 128;
  const int ls = lane >> 3;
  const int ss = lane & 7;

  f32x4 acc[4][4];
#pragma unroll
  for (int i = 0; i < 4; i++)
#pragma unroll
    for (int j = 0; j < 4; j++) acc[i][j] = (f32x4){0.f, 0.f, 0.f, 0.f};

  for (int kb = 0; kb < DIM; kb += 64) {
#pragma unroll
    for (int i = 0; i < 4; i++) {
      int c = wid * 4 + i;
      int r = c * 8 + ls;
      int goff = (ss * 16) ^ ((r & 7) << 4);
      const char* ga = (const char*)A + ((size_t)(rb + r) * DIM + kb) * 2 + goff;
      load_lds16(ga, smem + c * 1024);
      const char* gw = (const char*)Wt + ((size_t)(cb + r) * DIM + kb) * 2 + goff;
      load_lds16(gw, smem + 16384 + c * 1024);
    }
    __syncthreads();
#pragma unroll
    for (int kk = 0; kk < 2; kk++) {
      f16x8 a[4], b[4];
#pragma unroll
      for (int fm = 0; fm < 4; fm++) {
        int row = wr * 64 + fm * 16 + lr;
        int byt = row * 128 + ((kk * 64 + lk * 16) ^ ((row & 7) << 4));
        a[fm] = *(const f16x8*)(smem + byt);
      }
#pragma unroll
      for (int fn = 0; fn < 4; fn++) {
        int row = wc * 64 + fn * 16 + lr;
        int byt = row * 128 + ((kk * 64 + lk * 16) ^ ((row & 7) << 4));
        b[fn] = *(const f16x8*)(smem + 16384 + byt);
      }
#pragma unroll
      for (int fm = 0; fm < 4; fm++)
#pragma unroll
        for (int fn = 0; fn < 4; fn++)
          acc[fm][fn] = __builtin_amdgcn_mfma_f32_16x16x32_f16(a[fm], b[fn], acc[fm][fn], 0, 0, 0);
    }
    __syncthreads();
  }

  if (yv == nullptr) {
#pragma unroll
    for (int fn = 0; fn < 4; fn++) {
      int col = cb + wc * 64 + fn * 16 + lr;
      float bv = bias[col];
#pragma unroll
      for (int fm = 0; fm < 4; fm++) {
#pragma unroll
        for (int r = 0; r < 4; r++) {
          int row = rb + wr * 64 + fm * 16 + lk * 4 + r;
          if (row < N_NODES) {
            float v = acc[fm][fn][r] + bv;
            v = (v >= 0.f) ? v : NEG_SLOPE * v;
            v *= n_out[row];
            Y[(size_t)row * DIM + col] = (f16)v;
          }
        }
      }
    }
  } else {
    if (tid < 128) yred[tid] = 0.f;
    __syncthreads();
#pragma unroll
    for (int fm = 0; fm < 4; fm++) {
#pragma unroll
      for (int r = 0; r < 4; r++) {
        int rloc = wr * 64 + fm * 16 + lk * 4 + r;
        int row = rb + rloc;
        float p = 0.f;
#pragma unroll
        for (int fn = 0; fn < 4; fn++) {
          int col = cb + wc * 64 + fn * 16 + lr;
          float v = acc[fm][fn][r] + bias[col];
          v = (v >= 0.f) ? v : NEG_SLOPE * v;
          p += v * wt_vec[col];
        }
        if (row < N_NODES) atomicAdd(&yred[rloc], p * n_out[row]);
      }
    }
    __syncthreads();
    if (tid < 128) {
      int row = rb + tid;
      if (row < N_NODES) atomicAdd(&yv[row], yred[tid]);
    }
  }
}

// logits[i] = n_in[i]*(y[i] + sum y[src]) + c
__global__ void k_sagg(const float* __restrict__ y, const int* __restrict__ ell,
                       const int* __restrict__ cnt_i, const float* __restrict__ n_in,
                       const float* __restrict__ c_out, float* __restrict__ out) {
  int i = blockIdx.x * blockDim.x + threadIdx.x;
  if (i >= N_NODES) return;
  int deg = cnt_i[i];
  if (deg > SLOTS) deg = SLOTS;
  const int* erow = ell + (size_t)i * SLOTS;
  float s = y[i];
  int j = 0;
  for (; j + 8 <= deg; j += 8) {
    int4 a = *(const int4*)(erow + j);
    int4 b = *(const int4*)(erow + j + 4);
    s += y[a.x] + y[a.y] + y[a.z] + y[a.w];
    s += y[b.x] + y[b.y] + y[b.z] + y[b.w];
  }
  for (; j < deg; ++j) s += y[erow[j]];
  out[i] = n_in[i] * s + c_out[0];
}

extern "C" void kernel_launch(void* const* d_in, const int* in_sizes, int n_in_cnt,
                              void* d_out, int out_size, void* d_ws, size_t ws_size,
                              hipStream_t stream) {
  const float* weight = (const float*)d_in[0];
  const int* sig = (const int*)d_in[1];
  const int* src = (const int*)d_in[2];
  const int* dst = (const int*)d_in[3];
  const float* emb = (const float*)d_in[4];
  const float* linW = (const float*)d_in[5];
  const float* linb = (const float*)d_in[6];
  const float* W0 = (const float*)d_in[7];
  const float* b0 = (const float*)d_in[8];
  const float* W1 = (const float*)d_in[9];
  const float* b1 = (const float*)d_in[10];
  const float* W2 = (const float*)d_in[11];
  const float* b2 = (const float*)d_in[12];
  const float* pW = (const float*)d_in[13];
  const float* pb = (const float*)d_in[14];
  float* out = (float*)d_out;

  char* ws = (char*)d_ws;
  size_t off = 0;
  auto alloc = [&](size_t bytes) {
    void* p = ws + off;
    off += (bytes + 255) & ~(size_t)255;
    return p;
  };
  int* cnt_i = (int*)alloc((size_t)N_NODES * 4);   // cnt_i+yv: one memset
  float* yv = (float*)alloc((size_t)N_NODES * 4);
  float* n_out = (float*)alloc((size_t)N_NODES * 4);
  float* n_in = (float*)alloc((size_t)N_NODES * 4);
  int* ell = (int*)alloc((size_t)N_NODES * SLOTS * 4);
  f16* Wt = (f16*)alloc((size_t)2 * DIM * DIM * 2);
  float* wt_vec = (float*)alloc((size_t)DIM * 4);
  float* c_out = (float*)alloc(256);
  f16* B0 = (f16*)alloc((size_t)M_PAD * DIM * 2);
  f16* B1 = (f16*)alloc((size_t)M_PAD * DIM * 2);

  // P-way cnt_o partial histograms from remaining workspace (P in {1,2,4,8,16})
  size_t avail = (ws_size > off) ? (ws_size - off) : 0;
  int P = (int)(avail / ((size_t)N_NODES * 4));
  P = (P >= 16) ? 16 : (P >= 8) ? 8 : (P >= 4) ? 4 : (P >= 2) ? 2 : 1;
  int* cnt_op = (int*)(ws + off);

  dim3 blk(256);
  hipMemsetAsync(cnt_i, 0, (char*)n_out - (char*)cnt_i, stream);
  hipMemsetAsync(cnt_op, 0, (size_t)P * N_NODES * 4, stream);
  k_setup<<<B_FEAT, blk, 0, stream>>>(src, dst, cnt_op, P - 1, cnt_i, ell,
                                      W0, W1, Wt, W2, b2, pW, pb, wt_vec, c_out,
                                      weight, sig, emb, linW, linb, B0);
  k_norms<<<(N_NODES + 255) / 256, blk, 0, stream>>>(cnt_op, P, cnt_i, n_out, n_in);

  dim3 ggrid(DIM / 128, M_PAD / 128);
  // layer 1: spmm applies n_out (X unscaled); gemm applies leaky+n_out
  k_spmm<<<N_NODES / 4, blk, 0, stream>>>(B0, B1, ell, cnt_i, n_in, n_out);
  k_gemm<<<ggrid, blk, 0, stream>>>(B1, Wt, b0, n_out, B0, nullptr, nullptr);
  // layer 2 (X pre-scaled) + fused final GEMV
  k_spmm<<<N_NODES / 4, blk, 0, stream>>>(B0, B1, ell, cnt_i, n_in, nullptr);
  k_gemm<<<ggrid, blk, 0, stream>>>(B1, Wt + (size_t)DIM * DIM, b1, n_out, nullptr, wt_vec, yv);
  // layer-3 scalar aggregation
  k_sagg<<<(N_NODES + 255) / 256, blk, 0, stream>>>(yv, ell, cnt_i, n_in, c_out, out);
}

// Round 16
// 1611.917 us; speedup vs baseline: 1.0331x; 1.0145x over previous
//
#include <hip/hip_runtime.h>

#define N_NODES 100000
#define M_PAD 100096   // 782 * 128
#define N_EDGES 3200000
#define DIM 512
#define NEG_SLOPE 0.01f

// k_setup block partition
#define B_PRE 12500            // N_EDGES / 256
#define B_WT (B_PRE + 2048)    // 2*DIM*DIM / 256
#define B_WP (B_WT + 129)      // 516 wave-tasks / 4
#define B_FEAT (B_WP + 25000)  // N_NODES / 4

typedef _Float16 f16;
typedef _Float16 f16x8 __attribute__((ext_vector_type(8)));
typedef float f32x4 __attribute__((ext_vector_type(4)));

__device__ __forceinline__ void load_lds16(const void* g, void* l) {
  __builtin_amdgcn_global_load_lds(
      (const __attribute__((address_space(1))) void*)g,
      (__attribute__((address_space(3))) void*)l, 16, 0, 0);
}

// ---------------- fused setup ----------------
// cnt_op: P_O partial out-degree histograms. ELL: npi partitions (edge e ->
// partition e&pimask), each with its own cursor array -> 4x more distinct
// cache lines under RMW -> append contention / npi.
__global__ void k_setup(const int* __restrict__ src, const int* __restrict__ dst,
                        int* __restrict__ cnt_op, int pomask,
                        int* __restrict__ cnt_ip, int pimask, int slots,
                        int* __restrict__ ellp,
                        const float* __restrict__ W0, const float* __restrict__ W1,
                        f16* __restrict__ Wt,
                        const float* __restrict__ W2, const float* __restrict__ b2,
                        const float* __restrict__ pW, const float* __restrict__ pb,
                        float* __restrict__ wt_vec, float* __restrict__ c_out,
                        const float* __restrict__ weight, const int* __restrict__ sig,
                        const float* __restrict__ emb, const float* __restrict__ linW,
                        const float* __restrict__ linb, f16* __restrict__ Xs) {
  const int bid = blockIdx.x;
  const int tid = threadIdx.x;
  if (bid < B_PRE) {
    int e = bid * 256 + tid;
    int s = src[e];
    atomicAdd(&cnt_op[(size_t)(bid & pomask) * N_NODES + s], 1);
    int d = dst[e];
    int p = e & pimask;
    size_t row = (size_t)p * N_NODES + d;
    int c = atomicAdd(&cnt_ip[row], 1);
    if (c < slots) ellp[row * slots + c] = s;
  } else if (bid < B_WT) {
    int idx = (bid - B_PRE) * 256 + tid;
    int l = idx >> 18;
    int r = idx & 262143;
    int n = r >> 9, k = r & 511;
    const float* W = l ? W1 : W0;
    Wt[idx] = (f16)W[k * DIM + n];
  } else if (bid < B_WP) {
    int wid = tid >> 6, lane = tid & 63;
    int t = (bid - B_WT) * 4 + wid;
    if (t < DIM) {
      float s = 0.f;
#pragma unroll
      for (int n = 0; n < DIM; n += 64) s += W2[t * DIM + n + lane] * pW[n + lane];
#pragma unroll
      for (int off = 32; off; off >>= 1) s += __shfl_down(s, off, 64);
      if (lane == 0) wt_vec[t] = s;
    } else if (t == DIM) {
      float s = 0.f;
#pragma unroll
      for (int n = 0; n < DIM; n += 64) s += b2[n + lane] * pW[n + lane];
#pragma unroll
      for (int off = 32; off; off >>= 1) s += __shfl_down(s, off, 64);
      if (lane == 0) c_out[0] = s + pb[0];
    }
  } else {
    int wid = tid >> 6, lane = tid & 63;
    int node = (bid - B_WP) * 4 + wid;
    float w = weight[node];
    int sg = sig[node];
    float s0 = emb[sg * 2], s1 = emb[sg * 2 + 1];
    int d0 = lane * 8;
    f16x8 v;
#pragma unroll
    for (int k = 0; k < 8; k++) {
      int d = d0 + k;
      v[k] = (f16)(w * linW[d] + s0 * linW[DIM + d] + s1 * linW[2 * DIM + d] + linb[d]);
    }
    *(f16x8*)(Xs + (size_t)node * DIM + d0) = v;
  }
}

// n_out from P_O partials; n_in = sum of partition cursors (exact in-degree)
__global__ void k_norms(const int* __restrict__ cnt_op, int npo,
                        const int* __restrict__ cnt_ip, int npi,
                        float* __restrict__ n_out, float* __restrict__ n_in) {
  int i = blockIdx.x * blockDim.x + threadIdx.x;
  if (i < N_NODES) {
    int d = 0;
    for (int p = 0; p < npo; p++) d += cnt_op[(size_t)p * N_NODES + i];
    n_out[i] = rsqrtf((float)d + 1.0f);
    int di = 0;
    for (int p = 0; p < npi; p++) di += cnt_ip[(size_t)p * N_NODES + i];
    n_in[i] = rsqrtf((float)di + 1.0f);
  }
}

// ---------------- model ----------------

// A[i] = n_in[i] * (scale(i)*X[i] + sum_e scale(src)*X[src_e]);
// scale = n_out if n_out != null else 1. Wave per node; partitioned-ELL gather.
__global__ void k_spmm(const f16* __restrict__ Xs, f16* __restrict__ A,
                       const int* __restrict__ ellp, const int* __restrict__ cnt_ip,
                       int npi, int slots,
                       const float* __restrict__ n_in, const float* __restrict__ n_out) {
  int wid = threadIdx.x >> 6, lane = threadIdx.x & 63;
  int node = blockIdx.x * 4 + wid;
  int d0 = lane * 8;
  float acc[8];
  {
    f16x8 v = *(const f16x8*)(Xs + (size_t)node * DIM + d0);
    float ss = n_out ? n_out[node] : 1.f;
#pragma unroll
    for (int k = 0; k < 8; k++) acc[k] = ss * (float)v[k];
  }
  const f16* base = Xs + d0;
#pragma unroll 1
  for (int p = 0; p < npi; p++) {
    size_t row = (size_t)p * N_NODES + node;
    int deg = cnt_ip[row];
    if (deg > slots) deg = slots;
    const int* erow = ellp + row * slots;
    int j = 0;
    if (n_out) {
      for (; j + 4 <= deg; j += 4) {
        int ix[4];
#pragma unroll
        for (int u = 0; u < 4; u++) ix[u] = erow[j + u];
        float sc[4];
#pragma unroll
        for (int u = 0; u < 4; u++) sc[u] = n_out[ix[u]];
        f16x8 v[4];
#pragma unroll
        for (int u = 0; u < 4; u++) v[u] = *(const f16x8*)(base + (size_t)ix[u] * DIM);
#pragma unroll
        for (int u = 0; u < 4; u++)
#pragma unroll
          for (int k = 0; k < 8; k++) acc[k] += sc[u] * (float)v[u][k];
      }
      for (; j < deg; ++j) {
        int sn = erow[j];
        float sc = n_out[sn];
        f16x8 v = *(const f16x8*)(base + (size_t)sn * DIM);
#pragma unroll
        for (int k = 0; k < 8; k++) acc[k] += sc * (float)v[k];
      }
    } else {
      for (; j + 4 <= deg; j += 4) {
        int ix[4];
#pragma unroll
        for (int u = 0; u < 4; u++) ix[u] = erow[j + u];
        f16x8 v[4];
#pragma unroll
        for (int u = 0; u < 4; u++) v[u] = *(const f16x8*)(base + (size_t)ix[u] * DIM);
#pragma unroll
        for (int u = 0; u < 4; u++)
#pragma unroll
          for (int k = 0; k < 8; k++) acc[k] += (float)v[u][k];
      }
      for (; j < deg; ++j) {
        int sn = erow[j];
        f16x8 v = *(const f16x8*)(base + (size_t)sn * DIM);
#pragma unroll
        for (int k = 0; k < 8; k++) acc[k] += (float)v[k];
      }
    }
  }
  float ni = n_in[node];
  f16x8 o;
#pragma unroll
  for (int k = 0; k < 8; k++) o[k] = (f16)(acc[k] * ni);
  __builtin_nontemporal_store(o, (f16x8*)(A + (size_t)node * DIM + d0));
}

// yv==null: Y = n_out*leaky(A@W+b). else: yv[row] += n_out[row]*(leaky(A@W+b).wt_vec).
// LDS-staged 128x128 tile, BK=64, global_load_lds w16 w/ pre-swizzled source,
// XOR-swizzled ds_read. 256 thr = 4 waves (2x2), wave tile 64x64.
__global__ __launch_bounds__(256) void k_gemm(const f16* __restrict__ A, const f16* __restrict__ Wt,
                                              const float* __restrict__ bias,
                                              const float* __restrict__ n_out,
                                              f16* __restrict__ Y,
                                              const float* __restrict__ wt_vec,
                                              float* __restrict__ yv) {
  __shared__ __align__(1024) char smem[32768];
  __shared__ float yred[128];
  const int tid = threadIdx.x;
  const int wid = tid >> 6, lane = tid & 63;
  const int lr = lane & 15, lk = lane >> 4;
  const int wr = wid >> 1, wc = wid & 1;
  const int cb = blockIdx.x * 128;
  const int rb = blockIdx.y * 128;
  const int ls = lane >> 3;
  const int ss = lane & 7;

  f32x4 acc[4][4];
#pragma unroll
  for (int i = 0; i < 4; i++)
#pragma unroll
    for (int j = 0; j < 4; j++) acc[i][j] = (f32x4){0.f, 0.f, 0.f, 0.f};

  for (int kb = 0; kb < DIM; kb += 64) {
#pragma unroll
    for (int i = 0; i < 4; i++) {
      int c = wid * 4 + i;
      int r = c * 8 + ls;
      int goff = (ss * 16) ^ ((r & 7) << 4);
      const char* ga = (const char*)A + ((size_t)(rb + r) * DIM + kb) * 2 + goff;
      load_lds16(ga, smem + c * 1024);
      const char* gw = (const char*)Wt + ((size_t)(cb + r) * DIM + kb) * 2 + goff;
      load_lds16(gw, smem + 16384 + c * 1024);
    }
    __syncthreads();
#pragma unroll
    for (int kk = 0; kk < 2; kk++) {
      f16x8 a[4], b[4];
#pragma unroll
      for (int fm = 0; fm < 4; fm++) {
        int row = wr * 64 + fm * 16 + lr;
        int byt = row * 128 + ((kk * 64 + lk * 16) ^ ((row & 7) << 4));
        a[fm] = *(const f16x8*)(smem + byt);
      }
#pragma unroll
      for (int fn = 0; fn < 4; fn++) {
        int row = wc * 64 + fn * 16 + lr;
        int byt = row * 128 + ((kk * 64 + lk * 16) ^ ((row & 7) << 4));
        b[fn] = *(const f16x8*)(smem + 16384 + byt);
      }
#pragma unroll
      for (int fm = 0; fm < 4; fm++)
#pragma unroll
        for (int fn = 0; fn < 4; fn++)
          acc[fm][fn] = __builtin_amdgcn_mfma_f32_16x16x32_f16(a[fm], b[fn], acc[fm][fn], 0, 0, 0);
    }
    __syncthreads();
  }

  if (yv == nullptr) {
#pragma unroll
    for (int fn = 0; fn < 4; fn++) {
      int col = cb + wc * 64 + fn * 16 + lr;
      float bv = bias[col];
#pragma unroll
      for (int fm = 0; fm < 4; fm++) {
#pragma unroll
        for (int r = 0; r < 4; r++) {
          int row = rb + wr * 64 + fm * 16 + lk * 4 + r;
          if (row < N_NODES) {
            float v = acc[fm][fn][r] + bv;
            v = (v >= 0.f) ? v : NEG_SLOPE * v;
            v *= n_out[row];
            Y[(size_t)row * DIM + col] = (f16)v;
          }
        }
      }
    }
  } else {
    if (tid < 128) yred[tid] = 0.f;
    __syncthreads();
#pragma unroll
    for (int fm = 0; fm < 4; fm++) {
#pragma unroll
      for (int r = 0; r < 4; r++) {
        int rloc = wr * 64 + fm * 16 + lk * 4 + r;
        int row = rb + rloc;
        float p = 0.f;
#pragma unroll
        for (int fn = 0; fn < 4; fn++) {
          int col = cb + wc * 64 + fn * 16 + lr;
          float v = acc[fm][fn][r] + bias[col];
          v = (v >= 0.f) ? v : NEG_SLOPE * v;
          p += v * wt_vec[col];
        }
        if (row < N_NODES) atomicAdd(&yred[rloc], p * n_out[row]);
      }
    }
    __syncthreads();
    if (tid < 128) {
      int row = rb + tid;
      if (row < N_NODES) atomicAdd(&yv[row], yred[tid]);
    }
  }
}

// logits[i] = n_in[i]*(y[i] + sum y[src]) + c   (thread per node, partitioned ELL)
__global__ void k_sagg(const float* __restrict__ y, const int* __restrict__ ellp,
                       const int* __restrict__ cnt_ip, int npi, int slots,
                       const float* __restrict__ n_in,
                       const float* __restrict__ c_out, float* __restrict__ out) {
  int i = blockIdx.x * blockDim.x + threadIdx.x;
  if (i >= N_NODES) return;
  float s = y[i];
  for (int p = 0; p < npi; p++) {
    size_t row = (size_t)p * N_NODES + i;
    int deg = cnt_ip[row];
    if (deg > slots) deg = slots;
    const int* erow = ellp + row * slots;
    int j = 0;
    for (; j + 4 <= deg; j += 4) {
      int4 a = *(const int4*)(erow + j);
      s += y[a.x] + y[a.y] + y[a.z] + y[a.w];
    }
    for (; j < deg; ++j) s += y[erow[j]];
  }
  out[i] = n_in[i] * s + c_out[0];
}

extern "C" void kernel_launch(void* const* d_in, const int* in_sizes, int n_in_cnt,
                              void* d_out, int out_size, void* d_ws, size_t ws_size,
                              hipStream_t stream) {
  const float* weight = (const float*)d_in[0];
  const int* sig = (const int*)d_in[1];
  const int* src = (const int*)d_in[2];
  const int* dst = (const int*)d_in[3];
  const float* emb = (const float*)d_in[4];
  const float* linW = (const float*)d_in[5];
  const float* linb = (const float*)d_in[6];
  const float* W0 = (const float*)d_in[7];
  const float* b0 = (const float*)d_in[8];
  const float* W1 = (const float*)d_in[9];
  const float* b1 = (const float*)d_in[10];
  const float* W2 = (const float*)d_in[11];
  const float* b2 = (const float*)d_in[12];
  const float* pW = (const float*)d_in[13];
  const float* pb = (const float*)d_in[14];
  float* out = (float*)d_out;

  // Choose ELL partitioning: 4 partitions x 28 slots if workspace allows,
  // else the proven 1 x 80 layout.
  const size_t A256 = 255;
  auto rnd = [&](size_t b) { return (b + A256) & ~A256; };
  size_t fixed = rnd((size_t)N_NODES * 4)        // yv
               + rnd((size_t)N_NODES * 4) * 2    // n_out, n_in
               + rnd((size_t)2 * DIM * DIM * 2)  // Wt
               + rnd((size_t)DIM * 4) + rnd(256) // wt_vec, c_out
               + rnd((size_t)M_PAD * DIM * 2) * 2;  // B0, B1
  size_t need4 = fixed + rnd((size_t)4 * N_NODES * 4)              // cnt_ip
               + rnd((size_t)4 * N_NODES * 28 * 4)                 // ellp
               + (size_t)N_NODES * 4;                              // >=1 cnt_o part
  int NPI, SLOTS_P;
  if (ws_size >= need4) { NPI = 4; SLOTS_P = 28; }
  else { NPI = 1; SLOTS_P = 80; }

  char* ws = (char*)d_ws;
  size_t off = 0;
  auto alloc = [&](size_t bytes) {
    void* p = ws + off;
    off += rnd(bytes);
    return p;
  };
  int* cnt_ip = (int*)alloc((size_t)NPI * N_NODES * 4);  // cnt_ip+yv: one memset
  float* yv = (float*)alloc((size_t)N_NODES * 4);
  float* n_out = (float*)alloc((size_t)N_NODES * 4);
  float* n_in = (float*)alloc((size_t)N_NODES * 4);
  int* ellp = (int*)alloc((size_t)NPI * N_NODES * SLOTS_P * 4);
  f16* Wt = (f16*)alloc((size_t)2 * DIM * DIM * 2);
  float* wt_vec = (float*)alloc((size_t)DIM * 4);
  float* c_out = (float*)alloc(256);
  f16* B0 = (f16*)alloc((size_t)M_PAD * DIM * 2);
  f16* B1 = (f16*)alloc((size_t)M_PAD * DIM * 2);

  // cnt_o partial histograms from the remainder (P_O in {1,2,4,8,16})
  size_t avail = (ws_size > off) ? (ws_size - off) : 0;
  int PO = (int)(avail / ((size_t)N_NODES * 4));
  PO = (PO >= 16) ? 16 : (PO >= 8) ? 8 : (PO >= 4) ? 4 : (PO >= 2) ? 2 : 1;
  int* cnt_op = (int*)(ws + off);

  dim3 blk(256);
  hipMemsetAsync(cnt_ip, 0, (char*)n_out - (char*)cnt_ip, stream);  // cnt_ip+yv
  hipMemsetAsync(cnt_op, 0, (size_t)PO * N_NODES * 4, stream);
  k_setup<<<B_FEAT, blk, 0, stream>>>(src, dst, cnt_op, PO - 1,
                                      cnt_ip, NPI - 1, SLOTS_P, ellp,
                                      W0, W1, Wt, W2, b2, pW, pb, wt_vec, c_out,
                                      weight, sig, emb, linW, linb, B0);
  k_norms<<<(N_NODES + 255) / 256, blk, 0, stream>>>(cnt_op, PO, cnt_ip, NPI, n_out, n_in);

  dim3 ggrid(DIM / 128, M_PAD / 128);
  // layer 1: spmm applies n_out (X unscaled); gemm applies leaky+n_out
  k_spmm<<<N_NODES / 4, blk, 0, stream>>>(B0, B1, ellp, cnt_ip, NPI, SLOTS_P, n_in, n_out);
  k_gemm<<<ggrid, blk, 0, stream>>>(B1, Wt, b0, n_out, B0, nullptr, nullptr);
  // layer 2 (X pre-scaled) + fused final GEMV
  k_spmm<<<N_NODES / 4, blk, 0, stream>>>(B0, B1, ellp, cnt_ip, NPI, SLOTS_P, n_in, nullptr);
  k_gemm<<<ggrid, blk, 0, stream>>>(B1, Wt + (size_t)DIM * DIM, b1, n_out, nullptr, wt_vec, yv);
  // layer-3 scalar aggregation
  k_sagg<<<(N_NODES + 255) / 256, blk, 0, stream>>>(yv, ellp, cnt_ip, NPI, SLOTS_P, n_in, c_out, out);
}